// Round 6
// baseline (186.280 us; speedup 1.0000x reference)
//
#include <hip/hip_runtime.h>
#include <hip/hip_bf16.h>
#include <cstddef>
#include <cstdint>

#define Nn 12288
#define NTIL 32
#define TJ 384                 // j per tile; 1.5 KB per row per stage
#define LOG2E 1.44269504088896340736f

typedef __bf16 bf16x8 __attribute__((ext_vector_type(8)));
typedef float  f32x4  __attribute__((ext_vector_type(4)));
typedef int    i32x4  __attribute__((ext_vector_type(4)));

__device__ __forceinline__ void gload_lds16_nt(const void* g, void* l) {
    __builtin_amdgcn_global_load_lds(
        (const __attribute__((address_space(1))) void*)g,
        (__attribute__((address_space(3))) void*)l, 16, 0, 2 /*nt*/);
}
__device__ __forceinline__ void gload_lds4(const void* g, void* l) {
    __builtin_amdgcn_global_load_lds(
        (const __attribute__((address_space(1))) void*)g,
        (__attribute__((address_space(3))) void*)l, 4, 0, 0);
}

// ---------------------------------------------------------------------------
// Kernel 1 (verified): wh = x @ W; whB in MFMA-fragment order; src/dst
// prescaled by log2(e) for native exp2 in the attn kernel.
// ---------------------------------------------------------------------------
__global__ __launch_bounds__(256) void prep_kernel(
    const float* __restrict__ x, const float* __restrict__ W,
    const float* __restrict__ wa, __bf16* __restrict__ whB,
    float* __restrict__ src, float* __restrict__ dst)
{
    __shared__ float  Wl[64 * 64];
    __shared__ float  Xl[64 * 64];
    __shared__ __bf16 whl[64 * 72];
    int t = threadIdx.x;
    int R0 = blockIdx.x * 64;
    for (int i = t; i < 4096; i += 256) {
        Wl[i] = W[i];
        Xl[i] = x[(size_t)R0 * 64 + i];
    }
    __syncthreads();
    int c   = t & 63;
    int r16 = (t >> 6) * 16;
    float vals[16];
    #pragma unroll
    for (int k = 0; k < 16; ++k) vals[k] = 0.f;
    #pragma unroll 16
    for (int kk = 0; kk < 64; ++kk) {
        float wv = Wl[kk * 64 + c];
        #pragma unroll
        for (int k = 0; k < 16; ++k)
            vals[k] = fmaf(Xl[(r16 + k) * 64 + kk], wv, vals[k]);
    }
    #pragma unroll
    for (int k = 0; k < 16; ++k) whl[c * 72 + r16 + k] = (__bf16)vals[k];
    __syncthreads();
    if (t < 64) {
        float s = 0.f, d = 0.f;
        #pragma unroll 16
        for (int cc = 0; cc < 64; ++cc) {
            float v = (float)whl[cc * 72 + t];
            s = fmaf(v, wa[cc], s);
            d = fmaf(v, wa[64 + cc], d);
        }
        src[R0 + t] = s * LOG2E;
        dst[R0 + t] = d * LOG2E;
    }
    #pragma unroll
    for (int gg = 0; gg < 2; ++gg) {
        int gidx   = t * 2 + gg;
        int jc_loc = gidx >> 8;
        int q      = (gidx >> 6) & 3;
        int lane   = gidx & 63;
        int crow   = (lane & 15) + 16 * q;
        int jrow   = jc_loc * 32 + (lane >> 4) * 8;
        bf16x8 v = *(const bf16x8*)&whl[crow * 72 + jrow];
        int jc = blockIdx.x * 2 + jc_loc;
        *(bf16x8*)&whB[((size_t)(jc * 4 + q) * 64 + lane) * 8] = v;
    }
}

// ---------------------------------------------------------------------------
// Kernel 2: J=384 tiles. Mask tile packed [16][384] ints in LDS with XOR
// swizzle (pos = chunk ^ (row&7), 16B chunks): linear gload_lds dest +
// pre-swizzled per-lane SOURCE offsets; reads apply the same involution ->
// 2-way banks (free). dst: 2x gload_lds4/wave (512-float window, overread
// slack in ws). B: 12 asm dwordx4/wave, dbuf regs. Constant vmcnt(20).
// ---------------------------------------------------------------------------
__global__ __launch_bounds__(256, 3) void attn_kernel(
    const int* __restrict__ mask, const __bf16* __restrict__ whB,
    const float* __restrict__ src, const float* __restrict__ dstv,
    const float* __restrict__ bias, float* __restrict__ out)
{
    // ints: maskbuf[2][6144] at 0, 6144 ; dstbuf[2][512] at 12288, 12800
    __shared__ int lm[13312];

    int t    = threadIdx.x;
    int lane = t & 63;
    int wid  = t >> 6;
    int g    = blockIdx.x;
    int row  = lane & 15;
    int kg   = lane >> 4;

    float srow = src[g * 16 + row];
    asm volatile("" :: "v"(srow));

    bf16x8 vones;
    #pragma unroll
    for (int e = 0; e < 8; ++e) vones[e] = (__bf16)1.0f;

    // --- mask-stage per-lane source byte offsets (6 ops/wave, const/tile) ---
    int moff[6];
    #pragma unroll
    for (int i = 0; i < 6; ++i) {
        int k    = wid * 6 + i;            // global op 0..23
        int f    = k * 1024 + lane * 16;   // byte in packed 24576-B tile
        int r    = f / 1536;               // staged row 0..15
        int cpos = (f - r * 1536) >> 4;    // 16-B chunk position 0..95
        int cg   = cpos ^ (r & 7);         // source chunk (involution)
        moff[i]  = r * (Nn * 4) + cg * 16;
    }
    const char* mbase = (const char*)mask + (size_t)g * 16 * (Nn * 4);

    // --- compute-side mask LDS int indices (swizzled reads, const/tile) ---
    int s = row & 7;
    int mi0[3], mi1[3];
    #pragma unroll
    for (int cc = 0; cc < 3; ++cc) {
        int cb  = wid * 24 + cc * 8;
        mi0[cc] = row * 384 + (cb + ((kg * 2) ^ s)) * 4;
        mi1[cc] = row * 384 + (cb + ((kg * 2 + 1) ^ s)) * 4;
    }

    i32x4 bset[2][12];
    f32x4 acc0 = {0.f, 0.f, 0.f, 0.f}, acc1 = acc0, acc2 = acc0, acc3 = acc0;
    f32x4 accZ = acc0;

#define STAGE(B, TT)                                                          \
    do {                                                                      \
        _Pragma("unroll")                                                     \
        for (int i = 0; i < 6; ++i)                                           \
            gload_lds16_nt(mbase + (size_t)(TT) * 1536 + moff[i],             \
                           (char*)lm + (B) * 24576 + (wid * 6 + i) * 1024);   \
        _Pragma("unroll")                                                     \
        for (int jj = 0; jj < 2; ++jj)                                        \
            gload_lds4(dstv + (TT) * 384 + (wid * 2 + jj) * 64 + lane,        \
                       (char*)lm + 49152 + (B) * 2048 + (wid * 2 + jj) * 256);\
    } while (0)

#define BLOAD(P, TT)                                                          \
    do {                                                                      \
        const char* _b0 = (const char*)whB +                                  \
                          ((size_t)(TT) * 12 + wid * 3) * 4096 +              \
                          (size_t)lane * 16;                                  \
        const char* _b1 = _b0 + 4096;                                         \
        const char* _b2 = _b0 + 8192;                                         \
        asm volatile("global_load_dwordx4 %0, %1, off"                        \
                     : "=v"(bset[P][0]) : "v"(_b0));                          \
        asm volatile("global_load_dwordx4 %0, %1, off offset:1024"            \
                     : "=v"(bset[P][1]) : "v"(_b0));                          \
        asm volatile("global_load_dwordx4 %0, %1, off offset:2048"            \
                     : "=v"(bset[P][2]) : "v"(_b0));                          \
        asm volatile("global_load_dwordx4 %0, %1, off offset:3072"            \
                     : "=v"(bset[P][3]) : "v"(_b0));                          \
        asm volatile("global_load_dwordx4 %0, %1, off"                        \
                     : "=v"(bset[P][4]) : "v"(_b1));                          \
        asm volatile("global_load_dwordx4 %0, %1, off offset:1024"            \
                     : "=v"(bset[P][5]) : "v"(_b1));                          \
        asm volatile("global_load_dwordx4 %0, %1, off offset:2048"            \
                     : "=v"(bset[P][6]) : "v"(_b1));                          \
        asm volatile("global_load_dwordx4 %0, %1, off offset:3072"            \
                     : "=v"(bset[P][7]) : "v"(_b1));                          \
        asm volatile("global_load_dwordx4 %0, %1, off"                        \
                     : "=v"(bset[P][8]) : "v"(_b2));                          \
        asm volatile("global_load_dwordx4 %0, %1, off offset:1024"            \
                     : "=v"(bset[P][9]) : "v"(_b2));                          \
        asm volatile("global_load_dwordx4 %0, %1, off offset:2048"            \
                     : "=v"(bset[P][10]) : "v"(_b2));                         \
        asm volatile("global_load_dwordx4 %0, %1, off offset:3072"            \
                     : "=v"(bset[P][11]) : "v"(_b2));                         \
    } while (0)

#define COMPUTE(B, P)                                                         \
    do {                                                                      \
        _Pragma("unroll")                                                     \
        for (int cc = 0; cc < 3; ++cc) {                                      \
            i32x4 m0 = *(const i32x4*)&lm[(B) * 6144 + mi0[cc]];              \
            i32x4 m1 = *(const i32x4*)&lm[(B) * 6144 + mi1[cc]];              \
            const float* db = (const float*)&lm[12288 + (B) * 512 +           \
                                                wid * 96 + cc * 32 + kg * 8]; \
            f32x4 d0 = *(const f32x4*)(db);                                   \
            f32x4 d1 = *(const f32x4*)(db + 4);                               \
            bf16x8 pa;                                                        \
            _Pragma("unroll")                                                 \
            for (int e = 0; e < 4; ++e) {                                     \
                float f0 = srow + d0[e];                                      \
                f0 = fmaxf(f0, 0.01f * f0);                                   \
                f0 = (m0[e] > 0) ? f0 : -1000.f;                              \
                pa[e] = (__bf16)__builtin_amdgcn_exp2f(f0);                   \
                float f1 = srow + d1[e];                                      \
                f1 = fmaxf(f1, 0.01f * f1);                                   \
                f1 = (m1[e] > 0) ? f1 : -1000.f;                              \
                pa[4 + e] = (__bf16)__builtin_amdgcn_exp2f(f1);               \
            }                                                                 \
            acc0 = __builtin_amdgcn_mfma_f32_16x16x32_bf16(                   \
                pa, __builtin_bit_cast(bf16x8, bset[P][cc * 4 + 0]), acc0, 0, 0, 0); \
            acc1 = __builtin_amdgcn_mfma_f32_16x16x32_bf16(                   \
                pa, __builtin_bit_cast(bf16x8, bset[P][cc * 4 + 1]), acc1, 0, 0, 0); \
            acc2 = __builtin_amdgcn_mfma_f32_16x16x32_bf16(                   \
                pa, __builtin_bit_cast(bf16x8, bset[P][cc * 4 + 2]), acc2, 0, 0, 0); \
            acc3 = __builtin_amdgcn_mfma_f32_16x16x32_bf16(                   \
                pa, __builtin_bit_cast(bf16x8, bset[P][cc * 4 + 3]), acc3, 0, 0, 0); \
            accZ = __builtin_amdgcn_mfma_f32_16x16x32_bf16(                   \
                pa, vones, accZ, 0, 0, 0);                                    \
        }                                                                     \
    } while (0)

#define BODY_FULL(P)                                                          \
    do {                                                                      \
        STAGE((P) ^ 1, tt + 1);                                               \
        BLOAD((P) ^ 1, tt + 1);                                               \
        asm volatile("s_waitcnt vmcnt(20)" ::: "memory");                     \
        __builtin_amdgcn_sched_barrier(0);                                    \
        __builtin_amdgcn_s_barrier();                                         \
        __builtin_amdgcn_sched_barrier(0);                                    \
        COMPUTE(P, P);                                                        \
        __builtin_amdgcn_s_barrier();                                         \
        ++tt;                                                                 \
    } while (0)

    int tt = 0;
    STAGE(0, 0);
    BLOAD(0, 0);

    for (int it = 0; it < 15; ++it) {   // tiles 0..29
        BODY_FULL(0);
        BODY_FULL(1);
    }
    BODY_FULL(0);                       // tile 30 (stages 31 into buf 1)
    asm volatile("s_waitcnt vmcnt(0)" ::: "memory");
    __builtin_amdgcn_sched_barrier(0);
    __builtin_amdgcn_s_barrier();
    __builtin_amdgcn_sched_barrier(0);
    COMPUTE(1, 1);                      // tile 31

#undef BODY_FULL
#undef COMPUTE
#undef BLOAD
#undef STAGE

    // block reduce: 4 wave partials -> (16 x 64) tile, normalize, + bias
    __syncthreads();
    float* red  = (float*)lm;          // [4][1024]
    float* redz = red + 4096;          // [4][16]
    #pragma unroll
    for (int r = 0; r < 4; ++r) {
        int orow = kg * 4 + r;         // C/D: row = 4*(lane>>4)+reg, col = lane&15
        red[wid * 1024 + orow * 64 + row]      = acc0[r];
        red[wid * 1024 + orow * 64 + row + 16] = acc1[r];
        red[wid * 1024 + orow * 64 + row + 32] = acc2[r];
        red[wid * 1024 + orow * 64 + row + 48] = acc3[r];
    }
    if (row == 0) {
        #pragma unroll
        for (int r = 0; r < 4; ++r) redz[wid * 16 + kg * 4 + r] = accZ[r];
    }
    __syncthreads();
    #pragma unroll
    for (int k = 0; k < 4; ++k) {
        int idx = k * 256 + t;
        int i   = idx >> 6;
        float sv = red[idx] + red[1024 + idx] + red[2048 + idx] + red[3072 + idx];
        float z  = redz[i] + redz[16 + i] + redz[32 + i] + redz[48 + i];
        z = (z != 0.f) ? z : 1.f;
        out[(size_t)g * 1024 + idx] = sv / z + bias[idx & 63];
    }
}

extern "C" void kernel_launch(void* const* d_in, const int* in_sizes, int n_in,
                              void* d_out, int out_size, void* d_ws, size_t ws_size,
                              hipStream_t stream) {
    const float* x    = (const float*)d_in[0];
    const int*   mask = (const int*)d_in[1];
    const float* W    = (const float*)d_in[2];
    const float* wa   = (const float*)d_in[3];
    const float* bias = (const float*)d_in[4];
    float* out = (float*)d_out;

    char* ws = (char*)d_ws;
    const size_t whB_bytes = (size_t)Nn * 64 * 2;   // 1.5 MB
    const size_t vec_bytes = (size_t)Nn * 4;        // 48 KB
    __bf16* whB = (__bf16*)ws;
    float*  src = (float*)(ws + whB_bytes);
    float*  dst = (float*)(ws + whB_bytes + vec_bytes);
    // NOTE: dst is followed by free ws space; attn overreads <=512 B past it.

    prep_kernel<<<Nn / 64, 256, 0, stream>>>(x, W, wa, whB, src, dst);
    attn_kernel<<<Nn / 16, 256, 0, stream>>>(mask, whB, src, dst, bias, out);
}

// Round 11
// 147.740 us; speedup vs baseline: 1.2609x; 1.2609x over previous
//
#include <hip/hip_runtime.h>
#include <hip/hip_bf16.h>
#include <cstddef>
#include <cstdint>

#define Nn 12288
#define MSTRIDE 260        // ints per mask row in LDS; 260%32=4 -> 2-way banks (free)
#define DSTOFF (2 * 16 * MSTRIDE)   // int offset of dst slots in lm
#define LOG2E 1.44269504088896340736f

typedef __bf16 bf16x8 __attribute__((ext_vector_type(8)));
typedef float  f32x4  __attribute__((ext_vector_type(4)));
typedef int    i32x4  __attribute__((ext_vector_type(4)));

__device__ __forceinline__ void gload_lds16(const void* g, void* l) {
    __builtin_amdgcn_global_load_lds(
        (const __attribute__((address_space(1))) void*)g,
        (__attribute__((address_space(3))) void*)l, 16, 0, 0 /*A/B: was aux=2*/);
}
__device__ __forceinline__ void gload_lds4(const void* g, void* l) {
    __builtin_amdgcn_global_load_lds(
        (const __attribute__((address_space(1))) void*)g,
        (__attribute__((address_space(3))) void*)l, 4, 0, 0);
}

// ---------------------------------------------------------------------------
// Kernel 1 (verified, unchanged): wh = x @ W; whB in MFMA-fragment order;
// src/dst prescaled by log2(e) for native exp2.
// ---------------------------------------------------------------------------
__global__ __launch_bounds__(256) void prep_kernel(
    const float* __restrict__ x, const float* __restrict__ W,
    const float* __restrict__ wa, __bf16* __restrict__ whB,
    float* __restrict__ src, float* __restrict__ dst)
{
    __shared__ float  Wl[64 * 64];
    __shared__ float  Xl[64 * 64];
    __shared__ __bf16 whl[64 * 72];
    int t = threadIdx.x;
    int R0 = blockIdx.x * 64;
    for (int i = t; i < 4096; i += 256) {
        Wl[i] = W[i];
        Xl[i] = x[(size_t)R0 * 64 + i];
    }
    __syncthreads();
    int c   = t & 63;
    int r16 = (t >> 6) * 16;
    float vals[16];
    #pragma unroll
    for (int k = 0; k < 16; ++k) vals[k] = 0.f;
    #pragma unroll 16
    for (int kk = 0; kk < 64; ++kk) {
        float wv = Wl[kk * 64 + c];
        #pragma unroll
        for (int k = 0; k < 16; ++k)
            vals[k] = fmaf(Xl[(r16 + k) * 64 + kk], wv, vals[k]);
    }
    #pragma unroll
    for (int k = 0; k < 16; ++k) whl[c * 72 + r16 + k] = (__bf16)vals[k];
    __syncthreads();
    if (t < 64) {
        float s = 0.f, d = 0.f;
        #pragma unroll 16
        for (int cc = 0; cc < 64; ++cc) {
            float v = (float)whl[cc * 72 + t];
            s = fmaf(v, wa[cc], s);
            d = fmaf(v, wa[64 + cc], d);
        }
        src[R0 + t] = s * LOG2E;
        dst[R0 + t] = d * LOG2E;
    }
    #pragma unroll
    for (int gg = 0; gg < 2; ++gg) {
        int gidx   = t * 2 + gg;
        int jc_loc = gidx >> 8;
        int q      = (gidx >> 6) & 3;
        int lane   = gidx & 63;
        int crow   = (lane & 15) + 16 * q;
        int jrow   = jc_loc * 32 + (lane >> 4) * 8;
        bf16x8 v = *(const bf16x8*)&whl[crow * 72 + jrow];
        int jc = blockIdx.x * 2 + jc_loc;
        *(bf16x8*)&whB[((size_t)(jc * 4 + q) * 64 + lane) * 8] = v;
    }
}

// ---------------------------------------------------------------------------
// Kernel 2: EXACT R5 structure (141.8 us verified). Only deltas:
//   - mask staging aux 2 -> 0  (the A/B under test)
//   - MSTRIDE 264 -> 260       (4-way -> 2-way LDS banks, free)
// ---------------------------------------------------------------------------
__global__ __launch_bounds__(256) void attn_kernel(
    const int* __restrict__ mask, const __bf16* __restrict__ whB,
    const float* __restrict__ src, const float* __restrict__ dstv,
    const float* __restrict__ bias, float* __restrict__ out)
{
    __shared__ int lm[DSTOFF + 2 * 256];   // mask dbuf [2][16][260] + dst dbuf

    int t    = threadIdx.x;
    int lane = t & 63;
    int wid  = t >> 6;
    int g    = blockIdx.x;
    int row  = lane & 15;
    int kg   = lane >> 4;
    int jl   = kg * 8;

    float srow = src[g * 16 + row];
    asm volatile("" :: "v"(srow));   // resolve before pipeline starts

    bf16x8 vones;
    #pragma unroll
    for (int e = 0; e < 8; ++e) vones[e] = (__bf16)1.0f;

    i32x4 bset[2][8];
    f32x4 acc0 = {0.f, 0.f, 0.f, 0.f}, acc1 = acc0, acc2 = acc0, acc3 = acc0;
    f32x4 accZ = acc0;

#define STAGE(B, TT)                                                          \
    do {                                                                      \
        _Pragma("unroll")                                                     \
        for (int rr = 0; rr < 4; ++rr) {                                      \
            int rs = wid * 4 + rr;                                            \
            gload_lds16(mask + (size_t)(g * 16 + rs) * Nn + (TT) * 256 +      \
                            lane * 4,                                         \
                        &lm[(B) * 4160 + rs * MSTRIDE]);                      \
        }                                                                     \
        gload_lds4(dstv + (TT) * 256 + wid * 64 + lane,                       \
                   &lm[DSTOFF + (B) * 256 + wid * 64]);                       \
    } while (0)

#define BLOAD(P, TT)                                                          \
    do {                                                                      \
        const char* _b0 = (const char*)whB +                                  \
                          ((size_t)((TT) * 8 + wid * 2)) * 4096 +             \
                          (size_t)lane * 16;                                  \
        const char* _b1 = _b0 + 4096;                                         \
        asm volatile("global_load_dwordx4 %0, %1, off"                        \
                     : "=v"(bset[P][0]) : "v"(_b0));                          \
        asm volatile("global_load_dwordx4 %0, %1, off offset:1024"            \
                     : "=v"(bset[P][1]) : "v"(_b0));                          \
        asm volatile("global_load_dwordx4 %0, %1, off offset:2048"            \
                     : "=v"(bset[P][2]) : "v"(_b0));                          \
        asm volatile("global_load_dwordx4 %0, %1, off offset:3072"            \
                     : "=v"(bset[P][3]) : "v"(_b0));                          \
        asm volatile("global_load_dwordx4 %0, %1, off"                        \
                     : "=v"(bset[P][4]) : "v"(_b1));                          \
        asm volatile("global_load_dwordx4 %0, %1, off offset:1024"            \
                     : "=v"(bset[P][5]) : "v"(_b1));                          \
        asm volatile("global_load_dwordx4 %0, %1, off offset:2048"            \
                     : "=v"(bset[P][6]) : "v"(_b1));                          \
        asm volatile("global_load_dwordx4 %0, %1, off offset:3072"            \
                     : "=v"(bset[P][7]) : "v"(_b1));                          \
    } while (0)

#define COMPUTE(B, P)                                                         \
    do {                                                                      \
        const int*   mb = &lm[(B) * 4160 + row * MSTRIDE + wid * 64];         \
        const float* db = (const float*)&lm[DSTOFF + (B) * 256 + wid * 64];   \
        _Pragma("unroll")                                                     \
        for (int cc = 0; cc < 2; ++cc) {                                      \
            i32x4 m0 = *(const i32x4*)(mb + cc * 32 + jl);                    \
            i32x4 m1 = *(const i32x4*)(mb + cc * 32 + jl + 4);                \
            f32x4 d0 = *(const f32x4*)(db + cc * 32 + jl);                    \
            f32x4 d1 = *(const f32x4*)(db + cc * 32 + jl + 4);                \
            bf16x8 pa;                                                        \
            _Pragma("unroll")                                                 \
            for (int e = 0; e < 4; ++e) {                                     \
                float f0 = srow + d0[e];                                      \
                f0 = fmaxf(f0, 0.01f * f0);                                   \
                float w0 = __builtin_amdgcn_exp2f(f0);                        \
                w0 = (m0[e] > 0) ? w0 : 0.f;                                  \
                pa[e] = (__bf16)w0;                                           \
                float f1 = srow + d1[e];                                      \
                f1 = fmaxf(f1, 0.01f * f1);                                   \
                float w1 = __builtin_amdgcn_exp2f(f1);                        \
                w1 = (m1[e] > 0) ? w1 : 0.f;                                  \
                pa[4 + e] = (__bf16)w1;                                       \
            }                                                                 \
            acc0 = __builtin_amdgcn_mfma_f32_16x16x32_bf16(                   \
                pa, __builtin_bit_cast(bf16x8, bset[P][cc * 4 + 0]), acc0, 0, 0, 0); \
            acc1 = __builtin_amdgcn_mfma_f32_16x16x32_bf16(                   \
                pa, __builtin_bit_cast(bf16x8, bset[P][cc * 4 + 1]), acc1, 0, 0, 0); \
            acc2 = __builtin_amdgcn_mfma_f32_16x16x32_bf16(                   \
                pa, __builtin_bit_cast(bf16x8, bset[P][cc * 4 + 2]), acc2, 0, 0, 0); \
            acc3 = __builtin_amdgcn_mfma_f32_16x16x32_bf16(                   \
                pa, __builtin_bit_cast(bf16x8, bset[P][cc * 4 + 3]), acc3, 0, 0, 0); \
            accZ = __builtin_amdgcn_mfma_f32_16x16x32_bf16(                   \
                pa, vones, accZ, 0, 0, 0);                                    \
        }                                                                     \
    } while (0)

#define BODY_FULL(P)                                                          \
    do {                                                                      \
        STAGE((P) ^ 1, tt + 1);                                               \
        BLOAD((P) ^ 1, tt + 1);                                               \
        asm volatile("s_waitcnt vmcnt(13)" ::: "memory");                     \
        __builtin_amdgcn_sched_barrier(0);                                    \
        __builtin_amdgcn_s_barrier();                                         \
        __builtin_amdgcn_sched_barrier(0);                                    \
        COMPUTE(P, P);                                                        \
        __builtin_amdgcn_s_barrier();                                         \
        ++tt;                                                                 \
    } while (0)

    int tt = 0;
    STAGE(0, 0);      // prologue: tile 0 in flight
    BLOAD(0, 0);

    for (int it = 0; it < 23; ++it) {   // tiles 0..45
        BODY_FULL(0);
        BODY_FULL(1);
    }
    BODY_FULL(0);                       // tile 46 (stages 47 into buf 1)
    asm volatile("s_waitcnt vmcnt(0)" ::: "memory");
    __builtin_amdgcn_sched_barrier(0);
    __builtin_amdgcn_s_barrier();
    __builtin_amdgcn_sched_barrier(0);
    COMPUTE(1, 1);                      // tile 47

#undef BODY_FULL
#undef COMPUTE
#undef BLOAD
#undef STAGE

    // block reduce: 4 wave partials -> (16 x 64) tile, normalize, + bias
    __syncthreads();
    float* red  = (float*)lm;          // [4][1024]
    float* redz = red + 4096;          // [4][16]
    #pragma unroll
    for (int r = 0; r < 4; ++r) {
        int orow = kg * 4 + r;         // C/D: row = 4*(lane>>4)+reg, col = lane&15
        red[wid * 1024 + orow * 64 + row]      = acc0[r];
        red[wid * 1024 + orow * 64 + row + 16] = acc1[r];
        red[wid * 1024 + orow * 64 + row + 32] = acc2[r];
        red[wid * 1024 + orow * 64 + row + 48] = acc3[r];
    }
    if (row == 0) {
        #pragma unroll
        for (int r = 0; r < 4; ++r) redz[wid * 16 + kg * 4 + r] = accZ[r];
    }
    __syncthreads();
    #pragma unroll
    for (int k = 0; k < 4; ++k) {
        int idx = k * 256 + t;
        int i   = idx >> 6;
        float sv = red[idx] + red[1024 + idx] + red[2048 + idx] + red[3072 + idx];
        float z  = redz[i] + redz[16 + i] + redz[32 + i] + redz[48 + i];
        z = (z != 0.f) ? z : 1.f;
        out[(size_t)g * 1024 + idx] = sv / z + bias[idx & 63];
    }
}

extern "C" void kernel_launch(void* const* d_in, const int* in_sizes, int n_in,
                              void* d_out, int out_size, void* d_ws, size_t ws_size,
                              hipStream_t stream) {
    const float* x    = (const float*)d_in[0];
    const int*   mask = (const int*)d_in[1];
    const float* W    = (const float*)d_in[2];
    const float* wa   = (const float*)d_in[3];
    const float* bias = (const float*)d_in[4];
    float* out = (float*)d_out;

    char* ws = (char*)d_ws;
    const size_t whB_bytes = (size_t)Nn * 64 * 2;   // 1.5 MB
    const size_t vec_bytes = (size_t)Nn * 4;        // 48 KB
    __bf16* whB = (__bf16*)ws;
    float*  src = (float*)(ws + whB_bytes);
    float*  dst = (float*)(ws + whB_bytes + vec_bytes);

    prep_kernel<<<Nn / 64, 256, 0, stream>>>(x, W, wa, whB, src, dst);
    attn_kernel<<<Nn / 16, 256, 0, stream>>>(mask, whB, src, dst, bias, out);
}